// Round 1
// baseline (624.396 us; speedup 1.0000x reference)
//
#include <hip/hip_runtime.h>
#include <hip/hip_bf16.h>

typedef __bf16 bf16_t;
typedef bf16_t bf16x8 __attribute__((ext_vector_type(8)));
typedef float  f32x4  __attribute__((ext_vector_type(4)));

#define MFMA16(a, b, c) __builtin_amdgcn_mfma_f32_16x16x32_bf16((a), (b), (c), 0, 0, 0)

static constexpr int BH_N  = 16;     // B*H
static constexpr int S_LEN = 8192;
static constexpr int KD    = 128;
static constexpr int VD    = 128;
static constexpr int BT    = 64;     // chunk
static constexpr int NCH   = S_LEN / BT;   // 128
static constexpr int NT    = BH_N * NCH;   // 2048

// workspace layout (bytes); total ~176 MiB
static constexpr size_t WS_W_OFF   = 0;                                    // bf16 [NT][64][128]
static constexpr size_t WS_Q_OFF   = WS_W_OFF   + (size_t)NT*BT*KD*2;      // bf16 [NT][64][128] (q*eg)
static constexpr size_t WS_KRT_OFF = WS_Q_OFF   + (size_t)NT*BT*KD*2;      // bf16 [NT][128][64] (k*ratio, transposed)
static constexpr size_t WS_AQK_OFF = WS_KRT_OFF + (size_t)NT*KD*BT*2;      // bf16 [NT][64][64]
static constexpr size_t WS_U_OFF   = WS_AQK_OFF + (size_t)NT*BT*BT*2;      // f32  [NT][64][128]
static constexpr size_t WS_EGL_OFF = WS_U_OFF   + (size_t)NT*BT*KD*4;      // f32  [NT]

// ---------------------------------------------------------------------------
// Kernel 1: per-chunk precompute (fully parallel over 2048 tiles)
// ---------------------------------------------------------------------------
__global__ __launch_bounds__(256) void gdn_pre(
    const float* __restrict__ qg, const float* __restrict__ kg, const float* __restrict__ vg,
    const float* __restrict__ gg, const float* __restrict__ bg,
    bf16_t* __restrict__ wsW, bf16_t* __restrict__ wsQ, bf16_t* __restrict__ wsKrT,
    bf16_t* __restrict__ wsAqk, float* __restrict__ wsU, float* __restrict__ wsEgl)
{
    __shared__ bf16_t sKb[64][136];   // normalized k (bf16), padded: 272B rows, 16B-aligned
    __shared__ bf16_t sQb[64][136];   // normalized+scaled q
    __shared__ float  sA0[64][64];
    __shared__ float  sGc[64];
    __shared__ float  sEg[64];
    __shared__ float  sBeta[64];

    const int tid  = threadIdx.x;
    const int lane = tid & 63;
    const int wid  = tid >> 6;
    const int tile = blockIdx.x;
    const int bh   = tile >> 7;   // /NCH
    const int c    = tile & 127;
    const size_t rowbase = (size_t)bh * S_LEN + (size_t)c * BT;

    // gate cumsum (wave 0) + beta (wave 1)
    if (wid == 0) {
        float val = gg[rowbase + lane];
        #pragma unroll
        for (int off = 1; off < 64; off <<= 1) {
            float t = __shfl_up(val, off);
            if (lane >= off) val += t;
        }
        sGc[lane] = val;
        sEg[lane] = expf(val);
    } else if (wid == 1) {
        sBeta[lane] = bg[rowbase + lane];
    }

    // load + L2-normalize k and q (f32 math, store bf16)
    {
        const int r = tid >> 2;       // row 0..63
        const int p = tid & 3;        // 32-col quarter
        const float4* kp = reinterpret_cast<const float4*>(kg + (rowbase + r) * KD + p * 32);
        float4 kv[8];
        float ss = 0.f;
        #pragma unroll
        for (int ii = 0; ii < 8; ++ii) {
            kv[ii] = kp[ii];
            ss += kv[ii].x*kv[ii].x + kv[ii].y*kv[ii].y + kv[ii].z*kv[ii].z + kv[ii].w*kv[ii].w;
        }
        ss += __shfl_xor(ss, 1);
        ss += __shfl_xor(ss, 2);
        float inv = 1.f / (sqrtf(ss) + 1e-6f);
        #pragma unroll
        for (int ii = 0; ii < 8; ++ii) {
            int cb = p * 32 + ii * 4;
            sKb[r][cb+0] = (bf16_t)(kv[ii].x * inv);
            sKb[r][cb+1] = (bf16_t)(kv[ii].y * inv);
            sKb[r][cb+2] = (bf16_t)(kv[ii].z * inv);
            sKb[r][cb+3] = (bf16_t)(kv[ii].w * inv);
        }
        const float4* qp = reinterpret_cast<const float4*>(qg + (rowbase + r) * KD + p * 32);
        float4 qv[8];
        ss = 0.f;
        #pragma unroll
        for (int ii = 0; ii < 8; ++ii) {
            qv[ii] = qp[ii];
            ss += qv[ii].x*qv[ii].x + qv[ii].y*qv[ii].y + qv[ii].z*qv[ii].z + qv[ii].w*qv[ii].w;
        }
        ss += __shfl_xor(ss, 1);
        ss += __shfl_xor(ss, 2);
        inv = 0.08838834764831845f / (sqrtf(ss) + 1e-6f);   // scale = 1/sqrt(128)
        #pragma unroll
        for (int ii = 0; ii < 8; ++ii) {
            int cb = p * 32 + ii * 4;
            sQb[r][cb+0] = (bf16_t)(qv[ii].x * inv);
            sQb[r][cb+1] = (bf16_t)(qv[ii].y * inv);
            sQb[r][cb+2] = (bf16_t)(qv[ii].z * inv);
            sQb[r][cb+3] = (bf16_t)(qv[ii].w * inv);
        }
    }
    __syncthreads();

    // A0 = strict_tril(K K^T * exp(gi-gj)) * beta_i   (f32, to LDS)
    // Aqk = tril(Q K^T * exp(gi-gj))                  (bf16, to ws)
    {
        const int frow = lane & 15;
        const int kgrp = (lane >> 4) * 8;
        f32x4 accK[4], accQ[4];
        #pragma unroll
        for (int n = 0; n < 4; ++n) { accK[n] = (f32x4){0.f,0.f,0.f,0.f}; accQ[n] = (f32x4){0.f,0.f,0.f,0.f}; }
        #pragma unroll
        for (int kk = 0; kk < 4; ++kk) {
            bf16x8 aK = *(const bf16x8*)&sKb[wid*16 + frow][kk*32 + kgrp];
            bf16x8 aQ = *(const bf16x8*)&sQb[wid*16 + frow][kk*32 + kgrp];
            #pragma unroll
            for (int n = 0; n < 4; ++n) {
                bf16x8 b = *(const bf16x8*)&sKb[n*16 + frow][kk*32 + kgrp];
                accK[n] = MFMA16(aK, b, accK[n]);
                accQ[n] = MFMA16(aQ, b, accQ[n]);
            }
        }
        const int crow = wid*16 + (lane >> 4) * 4;
        bf16_t* aqkBase = wsAqk + (size_t)tile * BT * BT;
        #pragma unroll
        for (int n = 0; n < 4; ++n) {
            #pragma unroll
            for (int r4 = 0; r4 < 4; ++r4) {
                int i = crow + r4, j = n*16 + frow;
                float e = expf(fminf(sGc[i] - sGc[j], 0.f));
                sA0[i][j] = (j < i) ? accK[n][r4] * e * sBeta[i] : 0.f;
                float aq  = (j <= i) ? accQ[n][r4] * e : 0.f;
                aqkBase[i * BT + j] = (bf16_t)aq;
            }
        }
    }

    // qeg = q*eg ; krT[m][i] = k[i][m]*ratio_i ; eg_last
    {
        bf16_t* qb = wsQ   + (size_t)tile * BT * KD;
        bf16_t* kb = wsKrT + (size_t)tile * KD * BT;
        #pragma unroll
        for (int it = 0; it < 32; ++it) {
            int idx = tid + it * 256;                // 0..8191
            int i = idx >> 7, m = idx & 127;
            qb[idx] = (bf16_t)((float)sQb[i][m] * sEg[i]);
        }
        #pragma unroll
        for (int it = 0; it < 32; ++it) {
            int idx = tid + it * 256;
            int m = idx >> 6, i = idx & 63;
            float ratio = expf(sGc[63] - sGc[i]);    // eg_last/eg_i, <=1
            kb[idx] = (bf16_t)((float)sKb[i][m] * ratio);
        }
        if (tid == 0) wsEgl[tile] = sEg[63];
    }
    __syncthreads();

    // forward substitution: (I + A0) x = rhs ; thread t owns column t
    {
        float x[64];
        if (tid < 128) {
            #pragma unroll
            for (int i = 0; i < 64; ++i)
                x[i] = sBeta[i] * sEg[i] * (float)sKb[i][tid];
        } else {
            const float* vp = vg + rowbase * VD + (tid - 128);
            #pragma unroll
            for (int i = 0; i < 64; ++i)
                x[i] = sBeta[i] * vp[(size_t)i * VD];
        }
        #pragma unroll
        for (int i = 1; i < 64; ++i) {
            float acc = x[i];
            #pragma unroll
            for (int j = 0; j < i; ++j)
                acc = fmaf(-sA0[i][j], x[j], acc);
            x[i] = acc;
        }
        if (tid < 128) {
            bf16_t* wp = wsW + (size_t)tile * BT * KD + tid;
            #pragma unroll
            for (int i = 0; i < 64; ++i) wp[(size_t)i * KD] = (bf16_t)x[i];
        } else {
            float* up = wsU + (size_t)tile * BT * KD + (tid - 128);
            #pragma unroll
            for (int i = 0; i < 64; ++i) up[(size_t)i * KD] = x[i];
        }
    }
}

// ---------------------------------------------------------------------------
// Kernel 2: sequential chunk scan; grid = 16 bh x 4 V-slices (VB=32)
// ---------------------------------------------------------------------------
__global__ __launch_bounds__(256) void gdn_scan(
    const bf16_t* __restrict__ wsW, const bf16_t* __restrict__ wsQ,
    const bf16_t* __restrict__ wsKrT, const bf16_t* __restrict__ wsAqk,
    const float* __restrict__ wsU, const float* __restrict__ wsEgl,
    float* __restrict__ outO, float* __restrict__ outS)
{
    __shared__ bf16_t sW[64][136];
    __shared__ bf16_t sQ[64][136];
    __shared__ bf16_t sKrT[128][72];
    __shared__ bf16_t sAqk[64][72];
    __shared__ bf16_t sSbT[32][136];  // S^T bf16: [j][m]
    __shared__ bf16_t sVbT[32][72];   // v^T bf16: [j][i]
    __shared__ float  sS[128][33];    // state f32, +1 pad -> conflict-free transpose
    __shared__ float  sU[64][36];

    const int tid  = threadIdx.x;
    const int lane = tid & 63;
    const int wid  = tid >> 6;
    const int bh   = blockIdx.x >> 2;
    const int vb   = blockIdx.x & 3;
    const int col0 = vb * 32;
    const int frow = lane & 15;
    const int kgrp = (lane >> 4) * 8;

    {   // zero state
        float* sSf = &sS[0][0];
        for (int it = tid; it < 128 * 33; it += 256) sSf[it] = 0.f;
    }
    __syncthreads();

    for (int c = 0; c < NCH; ++c) {
        const int tile = bh * NCH + c;
        // ---- stage chunk operands to LDS
        {
            const ushort4* srcW = (const ushort4*)(wsW + (size_t)tile * BT * KD);
            const ushort4* srcQ = (const ushort4*)(wsQ + (size_t)tile * BT * KD);
            #pragma unroll
            for (int it = 0; it < 8; ++it) {
                int idx = tid + it * 256; int e0 = idx * 4; int rr = e0 >> 7; int m0 = e0 & 127;
                *(ushort4*)&sW[rr][m0] = srcW[idx];
                *(ushort4*)&sQ[rr][m0] = srcQ[idx];
            }
            const ushort4* srcKr = (const ushort4*)(wsKrT + (size_t)tile * KD * BT);
            #pragma unroll
            for (int it = 0; it < 8; ++it) {
                int idx = tid + it * 256; int e0 = idx * 4; int mm = e0 >> 6; int i0 = e0 & 63;
                *(ushort4*)&sKrT[mm][i0] = srcKr[idx];
            }
            const ushort4* srcAq = (const ushort4*)(wsAqk + (size_t)tile * BT * BT);
            #pragma unroll
            for (int it = 0; it < 4; ++it) {
                int idx = tid + it * 256; int e0 = idx * 4; int ii = e0 >> 6; int j0 = e0 & 63;
                *(ushort4*)&sAqk[ii][j0] = srcAq[idx];
            }
            const float* srcU = wsU + (size_t)tile * BT * KD;
            #pragma unroll
            for (int it = 0; it < 2; ++it) {
                int idx = tid + it * 256; int r = idx >> 3; int qq = idx & 7;
                *(float4*)&sU[r][qq * 4] = *(const float4*)(srcU + (size_t)r * KD + col0 + qq * 4);
            }
        }
        // ---- S f32 -> S^T bf16
        #pragma unroll
        for (int it = 0; it < 16; ++it) {
            int idx = tid + it * 256;   // 0..4095
            int j = idx >> 7, m = idx & 127;
            sSbT[j][m] = (bf16_t)sS[m][j];
        }
        __syncthreads();

        // ---- wS = w@S ; o_inter = qeg@S
        f32x4 accW[2], accO[2];
        accW[0] = (f32x4){0.f,0.f,0.f,0.f}; accW[1] = accW[0];
        accO[0] = accW[0];                  accO[1] = accW[0];
        #pragma unroll
        for (int kk = 0; kk < 4; ++kk) {
            bf16x8 aW = *(const bf16x8*)&sW[wid*16 + frow][kk*32 + kgrp];
            bf16x8 aQ = *(const bf16x8*)&sQ[wid*16 + frow][kk*32 + kgrp];
            #pragma unroll
            for (int n = 0; n < 2; ++n) {
                bf16x8 b = *(const bf16x8*)&sSbT[n*16 + frow][kk*32 + kgrp];
                accW[n] = MFMA16(aW, b, accW[n]);
                accO[n] = MFMA16(aQ, b, accO[n]);
            }
        }
        // v = u - wS  -> v^T bf16
        {
            const int crow = wid*16 + (lane >> 4) * 4;
            #pragma unroll
            for (int n = 0; n < 2; ++n)
                #pragma unroll
                for (int r4 = 0; r4 < 4; ++r4) {
                    int i = crow + r4, j = n*16 + frow;
                    sVbT[j][i] = (bf16_t)(sU[i][j] - accW[n][r4]);
                }
        }
        __syncthreads();

        // ---- o_intra = Aqk@v ; write o
        #pragma unroll
        for (int kk = 0; kk < 2; ++kk) {
            bf16x8 aA = *(const bf16x8*)&sAqk[wid*16 + frow][kk*32 + kgrp];
            #pragma unroll
            for (int n = 0; n < 2; ++n) {
                bf16x8 b = *(const bf16x8*)&sVbT[n*16 + frow][kk*32 + kgrp];
                accO[n] = MFMA16(aA, b, accO[n]);
            }
        }
        {
            const int crow = wid*16 + (lane >> 4) * 4;
            float* ob = outO + ((size_t)bh * S_LEN + (size_t)c * BT) * VD + col0;
            #pragma unroll
            for (int n = 0; n < 2; ++n)
                #pragma unroll
                for (int r4 = 0; r4 < 4; ++r4) {
                    int i = crow + r4, j = n*16 + frow;
                    ob[(size_t)i * VD + j] = accO[n][r4];
                }
        }
        // ---- S = egl*S + krT @ v
        {
            const float egl = wsEgl[tile];
            #pragma unroll
            for (int mt = 0; mt < 2; ++mt) {
                const int mrowA = wid*32 + mt*16 + frow;
                const int mrowC = wid*32 + mt*16 + (lane >> 4) * 4;
                f32x4 accS[2];
                #pragma unroll
                for (int n = 0; n < 2; ++n)
                    #pragma unroll
                    for (int r4 = 0; r4 < 4; ++r4)
                        accS[n][r4] = egl * sS[mrowC + r4][n*16 + frow];
                #pragma unroll
                for (int kk = 0; kk < 2; ++kk) {
                    bf16x8 aK = *(const bf16x8*)&sKrT[mrowA][kk*32 + kgrp];
                    #pragma unroll
                    for (int n = 0; n < 2; ++n) {
                        bf16x8 b = *(const bf16x8*)&sVbT[n*16 + frow][kk*32 + kgrp];
                        accS[n] = MFMA16(aK, b, accS[n]);
                    }
                }
                #pragma unroll
                for (int n = 0; n < 2; ++n)
                    #pragma unroll
                    for (int r4 = 0; r4 < 4; ++r4)
                        sS[mrowC + r4][n*16 + frow] = accS[n][r4];
            }
        }
        __syncthreads();
    }

    // final state Sf
    {
        float* sb = outS + (size_t)bh * KD * VD + col0;
        #pragma unroll
        for (int it = 0; it < 16; ++it) {
            int idx = tid + it * 256;
            int m = idx >> 5, j = idx & 31;
            sb[(size_t)m * VD + j] = sS[m][j];
        }
    }
}

// ---------------------------------------------------------------------------
extern "C" void kernel_launch(void* const* d_in, const int* in_sizes, int n_in,
                              void* d_out, int out_size, void* d_ws, size_t ws_size,
                              hipStream_t stream) {
    (void)in_sizes; (void)n_in; (void)out_size; (void)ws_size;
    const float* q    = (const float*)d_in[0];
    const float* k    = (const float*)d_in[1];
    const float* v    = (const float*)d_in[2];
    const float* g    = (const float*)d_in[3];
    const float* beta = (const float*)d_in[4];

    char* ws = (char*)d_ws;
    bf16_t* wsW   = (bf16_t*)(ws + WS_W_OFF);
    bf16_t* wsQ   = (bf16_t*)(ws + WS_Q_OFF);
    bf16_t* wsKrT = (bf16_t*)(ws + WS_KRT_OFF);
    bf16_t* wsAqk = (bf16_t*)(ws + WS_AQK_OFF);
    float*  wsU   = (float*)(ws + WS_U_OFF);
    float*  wsEgl = (float*)(ws + WS_EGL_OFF);

    float* outO = (float*)d_out;
    float* outS = outO + (size_t)BH_N * S_LEN * VD;

    gdn_pre<<<dim3(NT), dim3(256), 0, stream>>>(q, k, v, g, beta,
                                                wsW, wsQ, wsKrT, wsAqk, wsU, wsEgl);
    gdn_scan<<<dim3(BH_N * 4), dim3(256), 0, stream>>>(wsW, wsQ, wsKrT, wsAqk, wsU, wsEgl,
                                                       outO, outS);
}

// Round 2
// 504.438 us; speedup vs baseline: 1.2378x; 1.2378x over previous
//
#include <hip/hip_runtime.h>
#include <hip/hip_bf16.h>

typedef __bf16 bf16_t;
typedef bf16_t bf16x8 __attribute__((ext_vector_type(8)));
typedef bf16_t bf16x4 __attribute__((ext_vector_type(4)));
typedef float  f32x4  __attribute__((ext_vector_type(4)));

#define MFMA16(a, b, c) __builtin_amdgcn_mfma_f32_16x16x32_bf16((a), (b), (c), 0, 0, 0)

static constexpr int BH_N  = 16;     // B*H
static constexpr int S_LEN = 8192;
static constexpr int KD    = 128;
static constexpr int VD    = 128;
static constexpr int BT    = 64;     // chunk
static constexpr int NCH   = S_LEN / BT;   // 128
static constexpr int NT    = BH_N * NCH;   // 2048

// workspace layout (bytes); total ~176 MiB
static constexpr size_t WS_W_OFF   = 0;                                    // bf16 [NT][64][128]
static constexpr size_t WS_Q_OFF   = WS_W_OFF   + (size_t)NT*BT*KD*2;      // bf16 [NT][64][128] (q*eg)
static constexpr size_t WS_KRT_OFF = WS_Q_OFF   + (size_t)NT*BT*KD*2;      // bf16 [NT][128][64] (k*ratio, transposed)
static constexpr size_t WS_AQK_OFF = WS_KRT_OFF + (size_t)NT*KD*BT*2;      // bf16 [NT][64][64]
static constexpr size_t WS_U_OFF   = WS_AQK_OFF + (size_t)NT*BT*BT*2;      // f32  [NT][64][128]
static constexpr size_t WS_EGL_OFF = WS_U_OFF   + (size_t)NT*BT*KD*4;      // f32  [NT]

// ---------------------------------------------------------------------------
// Kernel 1: per-chunk precompute (fully parallel over 2048 tiles)
// ---------------------------------------------------------------------------
__global__ __launch_bounds__(256) void gdn_pre(
    const float* __restrict__ qg, const float* __restrict__ kg, const float* __restrict__ vg,
    const float* __restrict__ gg, const float* __restrict__ bg,
    bf16_t* __restrict__ wsW, bf16_t* __restrict__ wsQ, bf16_t* __restrict__ wsKrT,
    bf16_t* __restrict__ wsAqk, float* __restrict__ wsU, float* __restrict__ wsEgl)
{
    __shared__ bf16_t sKb[64][136];   // normalized k (bf16), padded: 272B rows, 16B-aligned
    __shared__ bf16_t sQb[64][136];   // normalized+scaled q
    __shared__ float  sA0[64][64];
    __shared__ float  sGc[64];
    __shared__ float  sEg[64];
    __shared__ float  sRatio[64];     // exp(gc63 - gc_i)
    __shared__ float  sBeta[64];

    const int tid  = threadIdx.x;
    const int lane = tid & 63;
    const int wid  = tid >> 6;
    const int tile = blockIdx.x;
    const int bh   = tile >> 7;   // /NCH
    const int c    = tile & 127;
    const size_t rowbase = (size_t)bh * S_LEN + (size_t)c * BT;

    // gate cumsum (wave 0) + beta (wave 1)
    if (wid == 0) {
        float val = gg[rowbase + lane];
        #pragma unroll
        for (int off = 1; off < 64; off <<= 1) {
            float t = __shfl_up(val, off);
            if (lane >= off) val += t;
        }
        float g63 = __shfl(val, 63);
        sGc[lane]    = val;
        sEg[lane]    = expf(val);
        sRatio[lane] = expf(g63 - val);
        if (lane == 0) wsEgl[tile] = expf(g63);
    } else if (wid == 1) {
        sBeta[lane] = bg[rowbase + lane];
    }

    // load + L2-normalize k and q (f32 math, store bf16)
    {
        const int r = tid >> 2;       // row 0..63
        const int p = tid & 3;        // 32-col quarter
        const float4* kp = reinterpret_cast<const float4*>(kg + (rowbase + r) * KD + p * 32);
        float4 kv[8];
        float ss = 0.f;
        #pragma unroll
        for (int ii = 0; ii < 8; ++ii) {
            kv[ii] = kp[ii];
            ss += kv[ii].x*kv[ii].x + kv[ii].y*kv[ii].y + kv[ii].z*kv[ii].z + kv[ii].w*kv[ii].w;
        }
        ss += __shfl_xor(ss, 1);
        ss += __shfl_xor(ss, 2);
        float inv = 1.f / (sqrtf(ss) + 1e-6f);
        #pragma unroll
        for (int ii = 0; ii < 8; ++ii) {
            int cb = p * 32 + ii * 4;
            sKb[r][cb+0] = (bf16_t)(kv[ii].x * inv);
            sKb[r][cb+1] = (bf16_t)(kv[ii].y * inv);
            sKb[r][cb+2] = (bf16_t)(kv[ii].z * inv);
            sKb[r][cb+3] = (bf16_t)(kv[ii].w * inv);
        }
        const float4* qp = reinterpret_cast<const float4*>(qg + (rowbase + r) * KD + p * 32);
        float4 qv[8];
        ss = 0.f;
        #pragma unroll
        for (int ii = 0; ii < 8; ++ii) {
            qv[ii] = qp[ii];
            ss += qv[ii].x*qv[ii].x + qv[ii].y*qv[ii].y + qv[ii].z*qv[ii].z + qv[ii].w*qv[ii].w;
        }
        ss += __shfl_xor(ss, 1);
        ss += __shfl_xor(ss, 2);
        inv = 0.08838834764831845f / (sqrtf(ss) + 1e-6f);   // scale = 1/sqrt(128)
        #pragma unroll
        for (int ii = 0; ii < 8; ++ii) {
            int cb = p * 32 + ii * 4;
            sQb[r][cb+0] = (bf16_t)(qv[ii].x * inv);
            sQb[r][cb+1] = (bf16_t)(qv[ii].y * inv);
            sQb[r][cb+2] = (bf16_t)(qv[ii].z * inv);
            sQb[r][cb+3] = (bf16_t)(qv[ii].w * inv);
        }
    }
    __syncthreads();

    // A0 = strict_tril(K K^T * exp(gi-gj)) * beta_i   (f32, to LDS)
    // Aqk = tril(Q K^T * exp(gi-gj))                  (bf16, to ws)
    {
        const int frow = lane & 15;
        const int kgrp = (lane >> 4) * 8;
        f32x4 accK[4], accQ[4];
        #pragma unroll
        for (int n = 0; n < 4; ++n) { accK[n] = (f32x4){0.f,0.f,0.f,0.f}; accQ[n] = (f32x4){0.f,0.f,0.f,0.f}; }
        #pragma unroll
        for (int kk = 0; kk < 4; ++kk) {
            bf16x8 aK = *(const bf16x8*)&sKb[wid*16 + frow][kk*32 + kgrp];
            bf16x8 aQ = *(const bf16x8*)&sQb[wid*16 + frow][kk*32 + kgrp];
            #pragma unroll
            for (int n = 0; n < 4; ++n) {
                bf16x8 b = *(const bf16x8*)&sKb[n*16 + frow][kk*32 + kgrp];
                accK[n] = MFMA16(aK, b, accK[n]);
                accQ[n] = MFMA16(aQ, b, accQ[n]);
            }
        }
        const int crow = wid*16 + (lane >> 4) * 4;
        bf16_t* aqkBase = wsAqk + (size_t)tile * BT * BT;
        #pragma unroll
        for (int n = 0; n < 4; ++n) {
            #pragma unroll
            for (int r4 = 0; r4 < 4; ++r4) {
                int i = crow + r4, j = n*16 + frow;
                float e = expf(fminf(sGc[i] - sGc[j], 0.f));
                sA0[i][j] = (j < i) ? accK[n][r4] * e * sBeta[i] : 0.f;
                float aq  = (j <= i) ? accQ[n][r4] * e : 0.f;
                aqkBase[i * BT + j] = (bf16_t)aq;
            }
        }
    }

    // qeg = q*eg (vectorized 16B) ; krT[m][i] = k[i][m]*ratio_i
    {
        bf16_t* qb = wsQ   + (size_t)tile * BT * KD;
        bf16_t* kb = wsKrT + (size_t)tile * KD * BT;
        #pragma unroll
        for (int it = 0; it < 4; ++it) {
            int e0 = (tid + it * 256) * 8;          // 0..8184
            int i = e0 >> 7, m0 = e0 & 127;
            float eg = sEg[i];
            bf16x8 src = *(const bf16x8*)&sQb[i][m0];
            bf16x8 dst;
            #pragma unroll
            for (int jj = 0; jj < 8; ++jj) dst[jj] = (bf16_t)((float)src[jj] * eg);
            *(bf16x8*)&qb[e0] = dst;
        }
        const int i  = tid & 63;
        const int mg = tid >> 6;
        float ratio = sRatio[i];
        #pragma unroll
        for (int it = 0; it < 4; ++it) {
            int m0 = mg * 8 + it * 32;
            bf16x8 s = *(const bf16x8*)&sKb[i][m0];
            #pragma unroll
            for (int jj = 0; jj < 8; ++jj)
                kb[(m0 + jj) * BT + i] = (bf16_t)((float)s[jj] * ratio);
        }
    }
    __syncthreads();

    // forward substitution: (I + A0) x = rhs ; thread t owns column t
    {
        float x[64];
        if (tid < 128) {
            #pragma unroll
            for (int i = 0; i < 64; ++i)
                x[i] = sBeta[i] * sEg[i] * (float)sKb[i][tid];
        } else {
            const float* vp = vg + rowbase * VD + (tid - 128);
            #pragma unroll
            for (int i = 0; i < 64; ++i)
                x[i] = sBeta[i] * vp[(size_t)i * VD];
        }
        #pragma unroll
        for (int i = 1; i < 64; ++i) {
            float acc = x[i];
            #pragma unroll
            for (int j = 0; j < i; ++j)
                acc = fmaf(-sA0[i][j], x[j], acc);
            x[i] = acc;
        }
        if (tid < 128) {
            bf16_t* wp = wsW + (size_t)tile * BT * KD + tid;
            #pragma unroll
            for (int i = 0; i < 64; ++i) wp[(size_t)i * KD] = (bf16_t)x[i];
        } else {
            float* up = wsU + (size_t)tile * BT * KD + (tid - 128);
            #pragma unroll
            for (int i = 0; i < 64; ++i) up[(size_t)i * KD] = x[i];
        }
    }
}

// ---------------------------------------------------------------------------
// Kernel 2: sequential chunk scan; 64 blocks = 16 bh x 4 V-slices (VB=32).
// All chunk operands load straight into per-wave MFMA fragment registers
// (double-buffered, prefetched one chunk ahead). State S is persistent f32
// C-fragment registers; only bf16 S^T lives in LDS.
// ---------------------------------------------------------------------------
struct Frag {
    bf16x8 w[4];     // W rows (A-frag)
    bf16x8 q[4];     // Q*eg rows (A-frag)
    bf16x8 kr[4];    // KrT rows (A-frag), [mt*2+kk]
    bf16x8 aq[2];    // Aqk rows (A-frag)
    float  u[8];     // U C-frag [n*4+r4]
    float  egl;
};

__global__ __launch_bounds__(256) void gdn_scan(
    const bf16_t* __restrict__ wsW, const bf16_t* __restrict__ wsQ,
    const bf16_t* __restrict__ wsKrT, const bf16_t* __restrict__ wsAqk,
    const float* __restrict__ wsU, const float* __restrict__ wsEgl,
    float* __restrict__ outO, float* __restrict__ outS)
{
    __shared__ bf16_t sSbT[32][136];  // S^T bf16: [v_col][k_row]
    __shared__ bf16_t sVbT[32][72];   // v^T bf16: [v_col][chunk_row]

    const int tid  = threadIdx.x;
    const int lane = tid & 63;
    const int wid  = tid >> 6;
    // XCD grouping: the 4 V-slice blocks of one bh land on one XCD (assumes
    // round-robin blockIdx->XCD). Bijective over 64 blocks.
    const int idx = blockIdx.x;
    const int xcd = idx & 7;
    const int vb  = (idx >> 3) & 3;
    const int bh  = xcd + ((idx >> 5) << 3);
    const int col0 = vb * 32;
    const int frow = lane & 15;
    const int hi   = lane >> 4;
    const int kgrp = hi * 8;
    const int rowWQ = wid * 16 + frow;   // A-frag row for W/Q/Aqk
    const int crow  = wid * 16 + hi * 4; // C-frag row base for o/v
    const int mrowA = wid * 32 + frow;   // A-frag row base for KrT (+mt*16)
    const int mrowC = wid * 32 + hi * 4; // C-frag row base for S (+mt*16)

    f32x4 Sreg[2][2];
    #pragma unroll
    for (int mt = 0; mt < 2; ++mt)
        #pragma unroll
        for (int n = 0; n < 2; ++n) Sreg[mt][n] = (f32x4){0.f,0.f,0.f,0.f};

    {   // zero S^T
        uint* z = (uint*)&sSbT[0][0];
        for (int i = tid; i < 32*136/2; i += 256) z[i] = 0u;
    }

#define PREFETCH(F, TILE) do {                                                   \
    const size_t _t = (TILE);                                                    \
    const bf16_t* pW = wsW + _t*BT*KD + rowWQ*KD + kgrp;                         \
    const bf16_t* pQ = wsQ + _t*BT*KD + rowWQ*KD + kgrp;                         \
    _Pragma("unroll") for (int kk = 0; kk < 4; ++kk) {                           \
        (F).w[kk] = *(const bf16x8*)(pW + kk*32);                                \
        (F).q[kk] = *(const bf16x8*)(pQ + kk*32);                                \
    }                                                                            \
    const bf16_t* pA = wsAqk + _t*BT*BT + rowWQ*BT + kgrp;                       \
    _Pragma("unroll") for (int kk = 0; kk < 2; ++kk)                             \
        (F).aq[kk] = *(const bf16x8*)(pA + kk*32);                               \
    const bf16_t* pK = wsKrT + _t*KD*BT + mrowA*BT + kgrp;                       \
    _Pragma("unroll") for (int mt = 0; mt < 2; ++mt)                             \
        _Pragma("unroll") for (int kk = 0; kk < 2; ++kk)                         \
            (F).kr[mt*2+kk] = *(const bf16x8*)(pK + mt*16*BT + kk*32);           \
    const float* pU = wsU + _t*BT*KD + (size_t)crow*KD + col0 + frow;            \
    _Pragma("unroll") for (int n = 0; n < 2; ++n)                                \
        _Pragma("unroll") for (int r4 = 0; r4 < 4; ++r4)                         \
            (F).u[n*4+r4] = pU[r4*KD + n*16];                                    \
    (F).egl = wsEgl[_t];                                                         \
} while (0)

#define STEP(CUR, NXT, C) do {                                                   \
    int _cn = (C) + 1; if (_cn > NCH-1) _cn = NCH-1;                             \
    PREFETCH(NXT, (size_t)bh*NCH + _cn);                                         \
    __syncthreads();  /* sSbT (and sVbT reuse) ready */                          \
    f32x4 accW[2], accO[2];                                                      \
    accW[0] = (f32x4){0.f,0.f,0.f,0.f}; accW[1] = accW[0];                       \
    accO[0] = accW[0];                  accO[1] = accW[0];                       \
    _Pragma("unroll") for (int kk = 0; kk < 4; ++kk) {                           \
        _Pragma("unroll") for (int n = 0; n < 2; ++n) {                          \
            bf16x8 bS = *(const bf16x8*)&sSbT[n*16 + frow][kk*32 + kgrp];        \
            accW[n] = MFMA16((CUR).w[kk], bS, accW[n]);                          \
            accO[n] = MFMA16((CUR).q[kk], bS, accO[n]);                          \
        }                                                                        \
    }                                                                            \
    _Pragma("unroll") for (int n = 0; n < 2; ++n) {                              \
        bf16x4 pk;                                                               \
        _Pragma("unroll") for (int r4 = 0; r4 < 4; ++r4)                         \
            pk[r4] = (bf16_t)((CUR).u[n*4+r4] - accW[n][r4]);                    \
        *(bf16x4*)&sVbT[n*16 + frow][crow] = pk;                                 \
    }                                                                            \
    __syncthreads();  /* sVbT ready */                                           \
    _Pragma("unroll") for (int kk = 0; kk < 2; ++kk) {                           \
        _Pragma("unroll") for (int n = 0; n < 2; ++n) {                          \
            bf16x8 bV = *(const bf16x8*)&sVbT[n*16 + frow][kk*32 + kgrp];        \
            accO[n] = MFMA16((CUR).aq[kk], bV, accO[n]);                         \
        }                                                                        \
    }                                                                            \
    {                                                                            \
        float* ob = outO + ((size_t)bh*S_LEN + (size_t)(C)*BT)*VD + col0;        \
        _Pragma("unroll") for (int n = 0; n < 2; ++n)                            \
            _Pragma("unroll") for (int r4 = 0; r4 < 4; ++r4)                     \
                ob[(size_t)(crow + r4)*VD + n*16 + frow] = accO[n][r4];          \
    }                                                                            \
    _Pragma("unroll") for (int mt = 0; mt < 2; ++mt) {                           \
        f32x4 accS[2];                                                           \
        _Pragma("unroll") for (int n = 0; n < 2; ++n)                            \
            _Pragma("unroll") for (int r4 = 0; r4 < 4; ++r4)                     \
                accS[n][r4] = (CUR).egl * Sreg[mt][n][r4];                       \
        _Pragma("unroll") for (int kk = 0; kk < 2; ++kk) {                       \
            _Pragma("unroll") for (int n = 0; n < 2; ++n) {                      \
                bf16x8 bV = *(const bf16x8*)&sVbT[n*16 + frow][kk*32 + kgrp];    \
                accS[n] = MFMA16((CUR).kr[mt*2+kk], bV, accS[n]);                \
            }                                                                    \
        }                                                                        \
        _Pragma("unroll") for (int n = 0; n < 2; ++n) {                          \
            bf16x4 pk;                                                           \
            _Pragma("unroll") for (int r4 = 0; r4 < 4; ++r4)                     \
                pk[r4] = (bf16_t)accS[n][r4];                                    \
            *(bf16x4*)&sSbT[n*16 + frow][mrowC + mt*16] = pk;                    \
            Sreg[mt][n] = accS[n];                                               \
        }                                                                        \
    }                                                                            \
} while (0)

    Frag fA, fB;
    PREFETCH(fA, (size_t)bh*NCH + 0);

    for (int c = 0; c < NCH; c += 2) {
        STEP(fA, fB, c);
        STEP(fB, fA, c + 1);
    }

    // final state Sf from registers
    {
        float* sb = outS + (size_t)bh * KD * VD + col0;
        #pragma unroll
        for (int mt = 0; mt < 2; ++mt)
            #pragma unroll
            for (int n = 0; n < 2; ++n)
                #pragma unroll
                for (int r4 = 0; r4 < 4; ++r4)
                    sb[(size_t)(mrowC + mt*16 + r4) * VD + n*16 + frow] = Sreg[mt][n][r4];
    }
#undef STEP
#undef PREFETCH
}

// ---------------------------------------------------------------------------
extern "C" void kernel_launch(void* const* d_in, const int* in_sizes, int n_in,
                              void* d_out, int out_size, void* d_ws, size_t ws_size,
                              hipStream_t stream) {
    (void)in_sizes; (void)n_in; (void)out_size; (void)ws_size;
    const float* q    = (const float*)d_in[0];
    const float* k    = (const float*)d_in[1];
    const float* v    = (const float*)d_in[2];
    const float* g    = (const float*)d_in[3];
    const float* beta = (const float*)d_in[4];

    char* ws = (char*)d_ws;
    bf16_t* wsW   = (bf16_t*)(ws + WS_W_OFF);
    bf16_t* wsQ   = (bf16_t*)(ws + WS_Q_OFF);
    bf16_t* wsKrT = (bf16_t*)(ws + WS_KRT_OFF);
    bf16_t* wsAqk = (bf16_t*)(ws + WS_AQK_OFF);
    float*  wsU   = (float*)(ws + WS_U_OFF);
    float*  wsEgl = (float*)(ws + WS_EGL_OFF);

    float* outO = (float*)d_out;
    float* outS = outO + (size_t)BH_N * S_LEN * VD;

    gdn_pre<<<dim3(NT), dim3(256), 0, stream>>>(q, k, v, g, beta,
                                                wsW, wsQ, wsKrT, wsAqk, wsU, wsEgl);
    gdn_scan<<<dim3(BH_N * 4), dim3(256), 0, stream>>>(wsW, wsQ, wsKrT, wsAqk, wsU, wsEgl,
                                                       outO, outS);
}